// Round 5
// baseline (87.107 us; speedup 1.0000x reference)
//
#include <hip/hip_runtime.h>
#include <stdint.h>

#define HASH_T 524288u
#define HASH_MASK (HASH_T - 1u)
#define PRIME1 2654435761u
#define PRIME2 805459861u

typedef float f32x4 __attribute__((ext_vector_type(4)));

// Output: [B][32][256][256] f32, channel c = 2*l + f.
// Thread = 4 consecutive pixels (b, i, j0..j0+3) for HALF the levels.
//   half0: levels 0..10  (coarse: corner fetches dedup'd across the 4 pixels)
//   half1: levels 11..15 (random: per-pixel fetches)
// Rationale: kernel is TA lane-throughput bound (~1 gather-lane/cy/CU);
// dedup + dwordx4 stores cut lane-memory-ops/pixel from 96 to ~47.
__global__ __launch_bounds__(256) void lia_hashgrid_kernel(
    const float* __restrict__ x0,        // [B]
    const float* __restrict__ y0,        // [B]
    const float* __restrict__ tables,    // [T][2]
    const uint32_t* __restrict__ seeds,  // [16]
    const float* __restrict__ level_N,   // [16]
    const int* __restrict__ tile_p,      // scalar
    float* __restrict__ out)             // [B][32][65536]
{
    const int gid = blockIdx.x * 256 + threadIdx.x;
    const int j0 = (gid & 63) << 2;       // pixel quad start
    const int i  = (gid >> 6) & 255;
    const int bh = gid >> 14;             // block-uniform
    const int half = bh & 1;
    const int b = bh >> 1;

    const float inv_tile = 1.0f / (float)(*tile_p);   // 1/1024, exact
    const float xb = x0[b];
    const float py = (float)i + y0[b];

    const float2* __restrict__ tab2 = (const float2*)tables;
    float* outp = out + (size_t)b * 32u * 65536u + (size_t)(i * 256 + j0);

    if (half == 0) {
        // ---- levels 0..7: 3 x-columns (d in {0,1}), 6 fetches ----
        #pragma unroll
        for (int l = 0; l < 8; ++l) {
            const float s = level_N[l] * inv_tile;
            const uint32_t seed = seeds[l];

            const float yn = py * s;
            const float fy = yn - floorf(yn);
            const uint32_t iy0 = (uint32_t)(int)floorf(yn);
            const uint32_t hy0 = iy0 * PRIME2;
            const uint32_t hy1 = hy0 + PRIME2;

            const float xn0 = ((float)j0 + xb) * s;
            const float flx0 = floorf(xn0);
            const uint32_t X = (uint32_t)(int)flx0;
            const uint32_t hx0 = X * PRIME1;
            const uint32_t hx1 = hx0 + PRIME1;
            const uint32_t hx2 = hx1 + PRIME1;

            const float2 t00 = tab2[(hx0 ^ hy0 ^ seed) & HASH_MASK];
            const float2 t10 = tab2[(hx1 ^ hy0 ^ seed) & HASH_MASK];
            const float2 t20 = tab2[(hx2 ^ hy0 ^ seed) & HASH_MASK];
            const float2 t01 = tab2[(hx0 ^ hy1 ^ seed) & HASH_MASK];
            const float2 t11 = tab2[(hx1 ^ hy1 ^ seed) & HASH_MASK];
            const float2 t21 = tab2[(hx2 ^ hy1 ^ seed) & HASH_MASK];

            const float gy = 1.0f - fy;
            float e0s[4], e1s[4];
            #pragma unroll
            for (int p = 0; p < 4; ++p) {
                const float xn = ((float)(j0 + p) + xb) * s;
                const float flx = floorf(xn);
                const float fx = xn - flx;
                const bool dd = ((int)flx - (int)flx0) != 0;   // d in {0,1}
                const float2 f00 = dd ? t10 : t00;
                const float2 f10 = dd ? t20 : t10;
                const float2 f01 = dd ? t11 : t01;
                const float2 f11 = dd ? t21 : t11;
                const float gx = 1.0f - fx;
                const float w00 = gx * gy, w10 = fx * gy;
                const float w01 = gx * fy, w11 = fx * fy;
                e0s[p] = w00 * f00.x + w10 * f10.x + w01 * f01.x + w11 * f11.x;
                e1s[p] = w00 * f00.y + w10 * f10.y + w01 * f01.y + w11 * f11.y;
            }
            f32x4 v0 = {e0s[0], e0s[1], e0s[2], e0s[3]};
            f32x4 v1 = {e1s[0], e1s[1], e1s[2], e1s[3]};
            __builtin_nontemporal_store(v0, (f32x4*)(outp + (size_t)(2 * l) * 65536u));
            __builtin_nontemporal_store(v1, (f32x4*)(outp + (size_t)(2 * l + 1) * 65536u));
        }
        // ---- levels 8..10: 5 x-columns (d in {0..3}), 10 fetches ----
        #pragma unroll
        for (int l = 8; l < 11; ++l) {
            const float s = level_N[l] * inv_tile;
            const uint32_t seed = seeds[l];

            const float yn = py * s;
            const float fy = yn - floorf(yn);
            const uint32_t iy0 = (uint32_t)(int)floorf(yn);
            const uint32_t hy0 = iy0 * PRIME2;
            const uint32_t hy1 = hy0 + PRIME2;

            const float xn0 = ((float)j0 + xb) * s;
            const float flx0 = floorf(xn0);
            const uint32_t X = (uint32_t)(int)flx0;
            const uint32_t hx0 = X * PRIME1;
            const uint32_t hx1 = hx0 + PRIME1;
            const uint32_t hx2 = hx1 + PRIME1;
            const uint32_t hx3 = hx2 + PRIME1;
            const uint32_t hx4 = hx3 + PRIME1;

            const float2 t0a = tab2[(hx0 ^ hy0 ^ seed) & HASH_MASK];
            const float2 t1a = tab2[(hx1 ^ hy0 ^ seed) & HASH_MASK];
            const float2 t2a = tab2[(hx2 ^ hy0 ^ seed) & HASH_MASK];
            const float2 t3a = tab2[(hx3 ^ hy0 ^ seed) & HASH_MASK];
            const float2 t4a = tab2[(hx4 ^ hy0 ^ seed) & HASH_MASK];
            const float2 t0b = tab2[(hx0 ^ hy1 ^ seed) & HASH_MASK];
            const float2 t1b = tab2[(hx1 ^ hy1 ^ seed) & HASH_MASK];
            const float2 t2b = tab2[(hx2 ^ hy1 ^ seed) & HASH_MASK];
            const float2 t3b = tab2[(hx3 ^ hy1 ^ seed) & HASH_MASK];
            const float2 t4b = tab2[(hx4 ^ hy1 ^ seed) & HASH_MASK];

            const float gy = 1.0f - fy;
            float e0s[4], e1s[4];
            #pragma unroll
            for (int p = 0; p < 4; ++p) {
                const float xn = ((float)(j0 + p) + xb) * s;
                const float flx = floorf(xn);
                const float fx = xn - flx;
                const int d = (int)flx - (int)flx0;            // 0..3
                const float2 f00 = d == 0 ? t0a : d == 1 ? t1a : d == 2 ? t2a : t3a;
                const float2 f10 = d == 0 ? t1a : d == 1 ? t2a : d == 2 ? t3a : t4a;
                const float2 f01 = d == 0 ? t0b : d == 1 ? t1b : d == 2 ? t2b : t3b;
                const float2 f11 = d == 0 ? t1b : d == 1 ? t2b : d == 2 ? t3b : t4b;
                const float gx = 1.0f - fx;
                const float w00 = gx * gy, w10 = fx * gy;
                const float w01 = gx * fy, w11 = fx * fy;
                e0s[p] = w00 * f00.x + w10 * f10.x + w01 * f01.x + w11 * f11.x;
                e1s[p] = w00 * f00.y + w10 * f10.y + w01 * f01.y + w11 * f11.y;
            }
            f32x4 v0 = {e0s[0], e0s[1], e0s[2], e0s[3]};
            f32x4 v1 = {e1s[0], e1s[1], e1s[2], e1s[3]};
            __builtin_nontemporal_store(v0, (f32x4*)(outp + (size_t)(2 * l) * 65536u));
            __builtin_nontemporal_store(v1, (f32x4*)(outp + (size_t)(2 * l + 1) * 65536u));
        }
    } else {
        // ---- levels 11..15: fully random, per-pixel fetches ----
        #pragma unroll
        for (int l = 11; l < 16; ++l) {
            const float s = level_N[l] * inv_tile;
            const uint32_t seed = seeds[l];

            const float yn = py * s;
            const float fy = yn - floorf(yn);
            const uint32_t iy0 = (uint32_t)(int)floorf(yn);
            const uint32_t hy0 = iy0 * PRIME2;
            const uint32_t hy1 = hy0 + PRIME2;
            const float gy = 1.0f - fy;

            float e0s[4], e1s[4];
            #pragma unroll
            for (int p = 0; p < 4; ++p) {
                const float xn = ((float)(j0 + p) + xb) * s;
                const float flx = floorf(xn);
                const float fx = xn - flx;
                const uint32_t ix0 = (uint32_t)(int)flx;
                const uint32_t hx0 = ix0 * PRIME1;
                const uint32_t hx1 = hx0 + PRIME1;

                const float2 f00 = tab2[(hx0 ^ hy0 ^ seed) & HASH_MASK];
                const float2 f10 = tab2[(hx1 ^ hy0 ^ seed) & HASH_MASK];
                const float2 f01 = tab2[(hx0 ^ hy1 ^ seed) & HASH_MASK];
                const float2 f11 = tab2[(hx1 ^ hy1 ^ seed) & HASH_MASK];

                const float gx = 1.0f - fx;
                const float w00 = gx * gy, w10 = fx * gy;
                const float w01 = gx * fy, w11 = fx * fy;
                e0s[p] = w00 * f00.x + w10 * f10.x + w01 * f01.x + w11 * f11.x;
                e1s[p] = w00 * f00.y + w10 * f10.y + w01 * f01.y + w11 * f11.y;
            }
            f32x4 v0 = {e0s[0], e0s[1], e0s[2], e0s[3]};
            f32x4 v1 = {e1s[0], e1s[1], e1s[2], e1s[3]};
            __builtin_nontemporal_store(v0, (f32x4*)(outp + (size_t)(2 * l) * 65536u));
            __builtin_nontemporal_store(v1, (f32x4*)(outp + (size_t)(2 * l + 1) * 65536u));
        }
    }
}

extern "C" void kernel_launch(void* const* d_in, const int* in_sizes, int n_in,
                              void* d_out, int out_size, void* d_ws, size_t ws_size,
                              hipStream_t stream) {
    const float*    x0      = (const float*)d_in[0];
    const float*    y0      = (const float*)d_in[1];
    const float*    tables  = (const float*)d_in[2];
    const uint32_t* seeds   = (const uint32_t*)d_in[3];
    const float*    level_N = (const float*)d_in[4];
    const int*      tile_p  = (const int*)d_in[6];   // complete_tile_size
    float*          out     = (float*)d_out;

    const int B = in_sizes[0];                     // 8
    const int n_threads = B * 2 * 256 * 64;        // 2 halves x 256 rows x 64 quads
    const int n_blocks = n_threads / 256;

    lia_hashgrid_kernel<<<n_blocks, 256, 0, stream>>>(
        x0, y0, tables, seeds, level_N, tile_p, out);
}